// Round 1
// 88.782 us; speedup vs baseline: 1.0116x; 1.0116x over previous
//
#include <hip/hip_runtime.h>
#include <math.h>

// ExtrudeNet fused kernel for MI355X (gfx950) — round 6 (single-kernel fusion).
// B=4, M=2048 points, K=64 primitives, C=64, NSEG=4, SAMPLE_RATE=16 -> S=64 curve samples.
// Inputs (float32): pts (B,M,3), pp (B,28,K), Wint (B,K,C), Uw (B,C), is_training (int, always 1).
// Output (float32, concatenated): occupancies (B,M) | primitive_sdf (B,M,K) | inter (B,M,C) | support (B,M,K).
//
// R6 theory: rocprof shows the timed window is dominated by two 256-MiB harness poison
// fills (~40.6 us each @ 82-83% HBM peak); our kernels are only ~8.6 us of the 89.8.
// So: fuse curve-table generation into the main kernel (kill kernel A, its launch, the
// workspace round-trip, and the 32 KB/block restage), pair curve samples into float4
// (ds_read_b64 x64 -> ds_read_b128 x32 in phase 1), and move om to wave shuffles
// (LDS 33 KB -> exactly 32 KB -> 5 blocks/CU).

#define NB 4
#define NM 2048
#define NK 64
#define NC 64
#define NS 64
#define PPB 4   // points per 256-thread block (1 wave per point)

// Offsets into flat output
#define OCC_OFF   0
#define SDF_OFF   8192        // NB*NM
#define INTER_OFF 532480      // 8192 + 524288
#define SUP_OFF   1056768     // 8192 + 2*524288

// theta = 2*pi/16 + atan(tan(2*pi/16)/3) = 0.5299027864949896 (double-accurate)
#define CT 0.86285621096f     // cos(theta)
#define ST 0.50544946275f     // sin(theta)

#define L2E_40  57.70780163555852f   // 40 * log2(e)
#define L2E_150 216.40425613334447f  // 150 * log2(e)

__global__ __launch_bounds__(256) void extrude_net_fused(
    const float* __restrict__ pts,
    const float* __restrict__ pp,
    const float* __restrict__ Wint,
    const float* __restrict__ Uw,
    float* __restrict__ out)
{
    // s_curve4[s2][k] = (x_{2s2}, y_{2s2}, x_{2s2+1}, y_{2s2+1}) for primitive k.
    // Exactly 32 KB -> 5 blocks/CU (160 KB LDS). Reused as Wb[64][64] (16 KB) in phase 2.
    __shared__ __align__(16) float4 s_curve4[NS / 2][NK];

    const int tid  = threadIdx.x;
    const int lane = tid & 63;
    const int wv   = tid >> 6;                 // wave id: phase 0 = segment, phase 1+ = point slot
    const int gpt  = blockIdx.x * PPB + wv;    // global point index in [0, B*M)
    const int b    = gpt >> 11;                // / 2048 (512 blocks per batch, never straddles)
    const float* __restrict__ ppb = pp + b * (28 * NK);
    const int k = lane;

    // ---- Phase 0: generate rational-bezier curve table in LDS (wave = segment) ----
    {
        const int seg = wv;                    // 0..3
        const float r0 = fabsf(ppb[(8 + seg * 3 + 0) * NK + k]);
        const float r1 = fabsf(ppb[(8 + seg * 3 + 1) * NK + k]);
        const float r2 = fabsf(ppb[(8 + seg * 3 + 2) * NK + k]);
        const float rn = fabsf(ppb[(8 + ((seg + 1) & 3) * 3 + 0) * NK + k]);
        const float w1 = fabsf(ppb[(20 + seg * 2 + 0) * NK + k]);
        const float w2 = fabsf(ppb[(20 + seg * 2 + 1) * NK + k]);

        // rotation by seg*90deg: (cosv,sinv); wave-uniform -> scalar selects, no arrays
        // (avoids runtime-indexed local arrays -> scratch).
        const float cosv = (seg == 0) ? 1.f : (seg == 2) ? -1.f : 0.f;
        const float sinv = (seg == 1) ? 1.f : (seg == 3) ? -1.f : 0.f;
        // P0 = rot(r0,0); P1 = rot(CT,ST)*r1; P2 = rot(ST,CT)*r2; P3 = rot(0,rn)
        const float P0x =  r0 * cosv,            P0y = r0 * sinv;
        const float P1x = (CT * cosv - ST * sinv) * r1, P1y = (CT * sinv + ST * cosv) * r1;
        const float P2x = (ST * cosv - CT * sinv) * r2, P2y = (ST * sinv + CT * cosv) * r2;
        const float P3x = -rn * sinv,            P3y = rn * cosv;

        #pragma unroll
        for (int j = 0; j < 16; j += 2) {
            float sx[2], sy[2];
            #pragma unroll
            for (int h = 0; h < 2; ++h) {
                // t, basis polys are literal constants after unroll
                const float t  = (float)(j + h) * 0.0625f;  // linspace(0,1,16,endpoint=False)
                const float u  = 1.f - t;
                const float b0 = u * u * u;
                const float b1 = 3.f * u * u * t;
                const float b2 = 3.f * u * t * t;
                const float b3 = t * t * t;
                const float wb1 = w1 * b1, wb2 = w2 * b2;
                const float inv = __builtin_amdgcn_rcpf(b0 + wb1 + wb2 + b3);
                sx[h] = (P0x * b0 + P1x * wb1 + P2x * wb2 + P3x * b3) * inv;
                sy[h] = (P0y * b0 + P1y * wb1 + P2y * wb2 + P3y * b3) * inv;
            }
            // lane k writes 16 B at k*16 + imm -> conflict-free ds_write_b128
            s_curve4[seg * 8 + (j >> 1)][k] = make_float4(sx[0], sy[0], sx[1], sy[1]);
        }
    }
    __syncthreads();

    // ---- Phase 1: per-primitive SDF; wave = one point, lane = primitive k ----
    const float ptx = pts[gpt * 3 + 0];
    const float pty = pts[gpt * 3 + 1];
    const float ptz = pts[gpt * 3 + 2];
    float om;   // 1 - occ = sigmoid(+150*sdf) for (point wv, primitive k)
    {
        const float q0 = ppb[0 * NK + k], q1 = ppb[1 * NK + k];
        const float q2 = ppb[2 * NK + k], q3 = ppb[3 * NK + k];
        const float trx = ppb[4 * NK + k], try_ = ppb[5 * NK + k], trz = ppb[6 * NK + k];
        const float h   = ppb[7 * NK + k];

        const float px = ptx - trx, py = pty - try_, pz = ptz - trz;
        const float inv = __builtin_amdgcn_rsqf(q0 * q0 + q1 * q1 + q2 * q2 + q3 * q3 + 1e-8f);
        const float w  = q0 * inv;
        const float vx = -q1 * inv, vy = -q2 * inv, vz = -q3 * inv;
        // rotate by conjugate: pl = p + w*t2 + cross(v, t2), t2 = 2*cross(v, p)
        const float t2x = 2.f * (vy * pz - vz * py);
        const float t2y = 2.f * (vz * px - vx * pz);
        const float t2z = 2.f * (vx * py - vy * px);
        const float plx = px + w * t2x + (vy * t2z - vz * t2y);
        const float ply = py + w * t2y + (vz * t2x - vx * t2z);
        const float plz = pz + w * t2z + (vx * t2y - vy * t2x);

        const float4* __restrict__ col = &s_curve4[0][k];  // col[s2*NK] = samples 2s2, 2s2+1

        const float4 c0 = col[0];
        const float ax = c0.x - plx, ay = c0.y - ply;      // rel of sample 0 (kept for wrap)
        float rx = c0.z - plx, ry = c0.w - ply;            // rel of sample 1
        const bool pos0 = ay > 0.f;
        bool apos = ry > 0.f;
        int wn = 0;
        // edge 0 -> 1
        {
            const float cr = ax * ry - ay * rx;
            wn += ((!pos0) & apos & (cr > 0.f)) ? 1 : 0;
            wn -= (pos0 & (!apos) & (cr < 0.f)) ? 1 : 0;
        }
        float d2a = ax * ax + ay * ay;
        float d2b = rx * rx + ry * ry;
        // FULL unroll: every ds_read_b128 offset is a compile-time immediate (s2*1024 B).
        // Two edges per iteration (independent d2a/d2b min chains, branchless '&' bools).
        #pragma unroll
        for (int s2 = 1; s2 < 32; ++s2) {
            const float4 cn = col[s2 * NK];
            const float nx0 = cn.x - plx, ny0 = cn.y - ply;
            const float nx1 = cn.z - plx, ny1 = cn.w - ply;
            const bool b0p = ny0 > 0.f;
            const bool b1p = ny1 > 0.f;
            const float cr0 = rx * ny0 - ry * nx0;         // edge (2s2-1 -> 2s2)
            const float cr1 = nx0 * ny1 - ny0 * nx1;       // edge (2s2 -> 2s2+1)
            wn += ((!apos) & b0p & (cr0 > 0.f)) ? 1 : 0;
            wn -= (apos & (!b0p) & (cr0 < 0.f)) ? 1 : 0;
            wn += ((!b0p) & b1p & (cr1 > 0.f)) ? 1 : 0;
            wn -= (b0p & (!b1p) & (cr1 < 0.f)) ? 1 : 0;
            d2a = fminf(d2a, nx0 * nx0 + ny0 * ny0);
            d2b = fminf(d2b, nx1 * nx1 + ny1 * ny1);
            apos = b1p; rx = nx1; ry = ny1;
        }
        // wrap edge: V63 -> V0 (both rel kept in registers)
        {
            const float cr = rx * ay - ry * ax;
            wn += ((!apos) & pos0 & (cr > 0.f)) ? 1 : 0;
            wn -= (apos & (!pos0) & (cr < 0.f)) ? 1 : 0;
        }
        const float dmin  = sqrtf(fminf(d2a, d2b) + 1e-12f);
        // sum(atan2) over closed polygon = 2*pi*wn exactly; |winding|>0.5 <=> wn != 0
        const float sdf2d = (wn != 0) ? -dmin : dmin;
        const float dz    = fabsf(plz) - fabsf(h);
        const float mx    = fmaxf(sdf2d, dz);
        const float e1    = fmaxf(sdf2d, 0.f);
        const float e2    = fmaxf(dz, 0.f);
        const float sdf   = fminf(mx, 0.f) + sqrtf(e1 * e1 + e2 * e2 + 1e-12f);

        out[SDF_OFF + gpt * NK + k] = sdf;
        out[SUP_OFF + gpt * NK + k] = dmin;
        // om = 1 - sigmoid(-150*sdf) = sigmoid(+150*sdf); rcp(inf)=0 so extremes are safe
        om = __builtin_amdgcn_rcpf(1.f + exp2f(-sdf * L2E_150));
    }
    __syncthreads();   // phase-1 LDS reads complete -> curve region is dead

    // ---- Stage Wb (16 KB) into the dead curve region: 1024 float4s, 4 per thread ----
    {
        const float4* __restrict__ wsrc = (const float4*)(Wint + b * (NK * NC));
        float4* wdst = (float4*)&s_curve4[0][0];
        #pragma unroll
        for (int i = 0; i < 4; ++i)
            wdst[i * 256 + tid] = wsrc[i * 256 + tid];
    }
    __syncthreads();

    // ---- Phase 2: intersection (softmax over k; logits -40*pre in [-40,0] so no max
    // tracking needed: exp2 range [2^-57.7, 1] is normal) + union (wave softmax over c).
    // om[kk] lives in lane kk of this wave -> __shfl broadcast, no LDS needed. ----
    {
        const int c = lane;
        const float* __restrict__ WbL = (const float*)&s_curve4[0][0];  // [NK][NC] in LDS
        float srun = 0.f, trun = 0.f;
        #pragma unroll
        for (int kk = 0; kk < NK; ++kk) {
            const float omk = __shfl(om, kk, 64);                // wave-uniform broadcast
            const float pre = fmaf(-WbL[kk * NC + c], omk, 1.f); // bank c%32, conflict-free
            const float e   = exp2f(pre * -L2E_40);
            srun += e;
            trun = fmaf(e, pre, trun);
        }
        const float inter = trun * __builtin_amdgcn_rcpf(srun);
        out[INTER_OFF + gpt * NC + c] = inter;

        // Union: softmax(pu*40)-weighted sum across the wave's 64 lanes
        const float pu = Uw[b * NC + c] * inter;
        float umax = pu;
        #pragma unroll
        for (int off = 32; off > 0; off >>= 1)
            umax = fmaxf(umax, __shfl_xor(umax, off, 64));
        const float e = exp2f((pu - umax) * L2E_40);
        float s1 = e, s2 = e * pu;
        #pragma unroll
        for (int off = 32; off > 0; off >>= 1) {
            s1 += __shfl_xor(s1, off, 64);
            s2 += __shfl_xor(s2, off, 64);
        }
        if (lane == 0) out[OCC_OFF + gpt] = s2 * __builtin_amdgcn_rcpf(s1);
    }
}

extern "C" void kernel_launch(void* const* d_in, const int* in_sizes, int n_in,
                              void* d_out, int out_size, void* d_ws, size_t ws_size,
                              hipStream_t stream) {
    const float* pts  = (const float*)d_in[0];
    const float* pp   = (const float*)d_in[1];
    const float* Wint = (const float*)d_in[2];
    const float* Uw   = (const float*)d_in[3];
    // d_in[4] = is_training (always 1 in this harness) -> training path hardcoded.
    float* out = (float*)d_out;
    (void)d_ws; (void)ws_size;   // workspace no longer used (curve table fused into LDS)

    const int grid = (NB * NM) / PPB;          // 2048 blocks x 256 threads
    extrude_net_fused<<<grid, 256, 0, stream>>>(pts, pp, Wint, Uw, out);
}

// Round 3
// 88.037 us; speedup vs baseline: 1.0201x; 1.0085x over previous
//
#include <hip/hip_runtime.h>
#include <math.h>

// ExtrudeNet fused kernel for MI355X (gfx950) — round 8 (= R7 resubmit; R7 bench was an
// infra failure: "container failed twice", no compile/pytest/profile output).
// B=4, M=2048 points, K=64 primitives, C=64, NSEG=4, SAMPLE_RATE=16 -> S=64 curve samples.
// Inputs (float32): pts (B,M,3), pp (B,28,K), Wint (B,K,C), Uw (B,C), is_training (int, always 1).
// Output (float32, concatenated): occupancies (B,M) | primitive_sdf (B,M,K) | inter (B,M,C) | support (B,M,K).
//
// Theory under test (from R6 counters: 45.3 us, VALUBusy 49%, Occupancy 33%, VGPR 44,
// bank-conflict 0, HBM 2% => latency-bound, not pipe-bound):
//  (a) PPB=8 / 512-thread blocks: 32 KB curve table amortized over 2x points; 4 blocks/CU
//      x 8 waves = 32 waves/CU (was LDS-capped at 20). __launch_bounds__(512,8) caps VGPR=64.
//  (b) explicit 2-pair-deep float4 prefetch pipeline in phase 1 (4 ds_read_b128 in flight,
//      immediate offsets) — VGPR 44 showed the compiler serialized load->wait->consume.
//  (c) phase-2 om via LDS float4 *broadcast* reads (1 ds_read_b128 per 4 kk) instead of
//      64 ds_bpermute shuffles: 128 -> 80 LDS wave-insts per point-wave.

#define NB 4
#define NM 2048
#define NK 64
#define NC 64
#define NS 64
#define PPB 8   // points per 512-thread block (1 wave per point)

// Offsets into flat output
#define OCC_OFF   0
#define SDF_OFF   8192        // NB*NM
#define INTER_OFF 532480      // 8192 + 524288
#define SUP_OFF   1056768     // 8192 + 2*524288

// theta = 2*pi/16 + atan(tan(2*pi/16)/3) = 0.5299027864949896 (double-accurate)
#define CT 0.86285621096f     // cos(theta)
#define ST 0.50544946275f     // sin(theta)

#define L2E_40  57.70780163555852f   // 40 * log2(e)
#define L2E_150 216.40425613334447f  // 150 * log2(e)

__global__ __launch_bounds__(512, 8) void extrude_net_fused(
    const float* __restrict__ pts,
    const float* __restrict__ pp,
    const float* __restrict__ Wint,
    const float* __restrict__ Uw,
    float* __restrict__ out)
{
    // s_curve4[s2][k] = (x_{2s2}, y_{2s2}, x_{2s2+1}, y_{2s2+1}) for primitive k. 32 KB.
    // Reused as Wb[64][64] (16 KB) in phase 2.  s_om: 1-occ per (point slot, primitive).
    __shared__ __align__(16) float4 s_curve4[NS / 2][NK];
    __shared__ __align__(16) float  s_om[PPB][NK];        // 2 KB -> total 34 KB -> 4 blocks/CU

    const int tid  = threadIdx.x;
    const int lane = tid & 63;
    const int wv   = tid >> 6;                 // wave id: phase 0 = (seg, half), phase 1+ = point slot
    const int gpt  = blockIdx.x * PPB + wv;    // global point index in [0, B*M)
    const int b    = gpt >> 11;                // / 2048 (256 blocks per batch, never straddles)
    const float* __restrict__ ppb = pp + b * (28 * NK);
    const int k = lane;

    // Hoist the (wave-uniform-address) point load to overlap its latency with phase 0.
    const float ptx = pts[gpt * 3 + 0];
    const float pty = pts[gpt * 3 + 1];
    const float ptz = pts[gpt * 3 + 2];

    // ---- Phase 0: rational-bezier curve table in LDS (2 waves per segment, 8 t's each) ----
    {
        const int seg = wv & 3;                // 0..3
        const int jb  = (wv >> 2) * 8;         // half 0: t-idx 0..7, half 1: 8..15
        const float r0 = fabsf(ppb[(8 + seg * 3 + 0) * NK + k]);
        const float r1 = fabsf(ppb[(8 + seg * 3 + 1) * NK + k]);
        const float r2 = fabsf(ppb[(8 + seg * 3 + 2) * NK + k]);
        const float rn = fabsf(ppb[(8 + ((seg + 1) & 3) * 3 + 0) * NK + k]);
        const float w1 = fabsf(ppb[(20 + seg * 2 + 0) * NK + k]);
        const float w2 = fabsf(ppb[(20 + seg * 2 + 1) * NK + k]);

        // rotation by seg*90deg (wave-uniform scalar selects, no runtime-indexed arrays)
        const float cosv = (seg == 0) ? 1.f : (seg == 2) ? -1.f : 0.f;
        const float sinv = (seg == 1) ? 1.f : (seg == 3) ? -1.f : 0.f;
        const float P0x =  r0 * cosv,                   P0y = r0 * sinv;
        const float P1x = (CT * cosv - ST * sinv) * r1, P1y = (CT * sinv + ST * cosv) * r1;
        const float P2x = (ST * cosv - CT * sinv) * r2, P2y = (ST * sinv + CT * cosv) * r2;
        const float P3x = -rn * sinv,                   P3y = rn * cosv;

        #pragma unroll
        for (int j0 = 0; j0 < 8; j0 += 2) {
            const int j = jb + j0;
            float sx[2], sy[2];
            #pragma unroll
            for (int h = 0; h < 2; ++h) {
                const float t  = (float)(j + h) * 0.0625f;  // linspace(0,1,16,endpoint=False)
                const float u  = 1.f - t;
                const float b0 = u * u * u;
                const float b1 = 3.f * u * u * t;
                const float b2 = 3.f * u * t * t;
                const float b3 = t * t * t;
                const float wb1 = w1 * b1, wb2 = w2 * b2;
                const float inv = __builtin_amdgcn_rcpf(b0 + wb1 + wb2 + b3);
                sx[h] = (P0x * b0 + P1x * wb1 + P2x * wb2 + P3x * b3) * inv;
                sy[h] = (P0y * b0 + P1y * wb1 + P2y * wb2 + P3y * b3) * inv;
            }
            // lane k writes 16 B at k*16 + imm -> conflict-free ds_write_b128
            s_curve4[seg * 8 + (j >> 1)][k] = make_float4(sx[0], sy[0], sx[1], sy[1]);
        }
    }
    __syncthreads();

    // ---- Phase 1: per-primitive SDF; wave = one point, lane = primitive k ----
    {
        const float q0 = ppb[0 * NK + k], q1 = ppb[1 * NK + k];
        const float q2 = ppb[2 * NK + k], q3 = ppb[3 * NK + k];
        const float trx = ppb[4 * NK + k], try_ = ppb[5 * NK + k], trz = ppb[6 * NK + k];
        const float h   = ppb[7 * NK + k];

        const float px = ptx - trx, py = pty - try_, pz = ptz - trz;
        const float inv = __builtin_amdgcn_rsqf(q0 * q0 + q1 * q1 + q2 * q2 + q3 * q3 + 1e-8f);
        const float w  = q0 * inv;
        const float vx = -q1 * inv, vy = -q2 * inv, vz = -q3 * inv;
        // rotate by conjugate: pl = p + w*t2 + cross(v, t2), t2 = 2*cross(v, p)
        const float t2x = 2.f * (vy * pz - vz * py);
        const float t2y = 2.f * (vz * px - vx * pz);
        const float t2z = 2.f * (vx * py - vy * px);
        const float plx = px + w * t2x + (vy * t2z - vz * t2y);
        const float ply = py + w * t2y + (vz * t2x - vx * t2z);
        const float plz = pz + w * t2z + (vx * t2y - vy * t2x);
        const float dz  = fabsf(plz) - fabsf(h);   // fold z-extrusion early (frees plz, h)

        const float4* __restrict__ col = &s_curve4[0][k];  // col[s2*NK] = samples 2s2, 2s2+1

        // Prologue: sample pair 0 + prefetch pairs 1,2 (4 ds_read_b128 in flight max)
        const float4 c0v = col[0];
        float4 cA = col[1 * NK];
        float4 cB = col[2 * NK];

        const float ax = c0v.x - plx, ay = c0v.y - ply;    // rel of sample 0 (kept for wrap)
        float rx = c0v.z - plx, ry = c0v.w - ply;          // rel of sample 1
        const bool pos0 = ay > 0.f;
        bool apos = ry > 0.f;
        int wn = 0;
        // edge 0 -> 1
        {
            const float cr = ax * ry - ay * rx;
            wn += ((!pos0) & apos & (cr > 0.f)) ? 1 : 0;
            wn -= (pos0 & (!apos) & (cr < 0.f)) ? 1 : 0;
        }
        float d2a = ax * ax + ay * ay;
        float d2b = rx * rx + ry * ry;

        // Two edges per float4 (branchless '&' bools, independent d2a/d2b min chains)
        auto PROC = [&](const float4 cn) {
            const float nx0 = cn.x - plx, ny0 = cn.y - ply;
            const float nx1 = cn.z - plx, ny1 = cn.w - ply;
            const bool b0p = ny0 > 0.f;
            const bool b1p = ny1 > 0.f;
            const float cr0 = rx * ny0 - ry * nx0;         // edge (2s2-1 -> 2s2)
            const float cr1 = nx0 * ny1 - ny0 * nx1;       // edge (2s2 -> 2s2+1)
            wn += ((!apos) & b0p & (cr0 > 0.f)) ? 1 : 0;
            wn -= (apos & (!b0p) & (cr0 < 0.f)) ? 1 : 0;
            wn += ((!b0p) & b1p & (cr1 > 0.f)) ? 1 : 0;
            wn -= (b0p & (!b1p) & (cr1 < 0.f)) ? 1 : 0;
            d2a = fminf(d2a, nx0 * nx0 + ny0 * ny0);
            d2b = fminf(d2b, nx1 * nx1 + ny1 * ny1);
            apos = b1p; rx = nx1; ry = ny1;
        };

        // Software pipeline, fully unrolled: process pairs (s2, s2+1) while prefetching
        // (s2+2, s2+3). All ds_read_b128 offsets are compile-time immediates.
        #pragma unroll
        for (int s2 = 1; s2 <= 29; s2 += 2) {
            float4 cC = cA, cD = cB;
            if (s2 + 2 < 32) cC = col[(s2 + 2) * NK];
            if (s2 + 3 < 32) cD = col[(s2 + 3) * NK];
            PROC(cA);
            PROC(cB);
            cA = cC; cB = cD;
        }
        PROC(cA);   // pair 31 (samples 62,63)

        // wrap edge: V63 -> V0 (both rel kept in registers)
        {
            const float cr = rx * ay - ry * ax;
            wn += ((!apos) & pos0 & (cr > 0.f)) ? 1 : 0;
            wn -= (apos & (!pos0) & (cr < 0.f)) ? 1 : 0;
        }
        const float dmin  = sqrtf(fminf(d2a, d2b) + 1e-12f);
        // sum(atan2) over closed polygon = 2*pi*wn exactly; |winding|>0.5 <=> wn != 0
        const float sdf2d = (wn != 0) ? -dmin : dmin;
        const float mx    = fmaxf(sdf2d, dz);
        const float e1    = fmaxf(sdf2d, 0.f);
        const float e2    = fmaxf(dz, 0.f);
        const float sdf   = fminf(mx, 0.f) + sqrtf(e1 * e1 + e2 * e2 + 1e-12f);

        out[SDF_OFF + gpt * NK + k] = sdf;
        out[SUP_OFF + gpt * NK + k] = dmin;
        // om = 1 - sigmoid(-150*sdf) = sigmoid(+150*sdf); rcp(inf)=0 so extremes are safe
        s_om[wv][k] = __builtin_amdgcn_rcpf(1.f + exp2f(-sdf * L2E_150));
    }
    __syncthreads();   // phase-1 LDS reads complete -> curve region is dead; s_om visible

    // ---- Stage Wb (16 KB) into the dead curve region: 1024 float4s, 2 per thread ----
    {
        const float4* __restrict__ wsrc = (const float4*)(Wint + b * (NK * NC));
        float4* wdst = (float4*)&s_curve4[0][0];
        #pragma unroll
        for (int i = 0; i < 2; ++i)
            wdst[i * 512 + tid] = wsrc[i * 512 + tid];
    }
    __syncthreads();

    // ---- Phase 2: intersection (softmax over k; logits -40*pre in [-40,0] so no max
    // tracking needed: exp2 range [2^-57.7, 1] is normal) + union (wave softmax over c).
    // om[4kk..4kk+3] read as one wave-uniform ds_read_b128 broadcast per 4 kk. ----
    {
        const int c = lane;
        const float*  __restrict__ WbL  = (const float*)&s_curve4[0][0];   // [NK][NC] in LDS
        const float4* __restrict__ om4p = (const float4*)&s_om[wv][0];
        float srun = 0.f, trun = 0.f;
        auto ACC = [&](float omk, int kk) {
            const float pre = fmaf(-WbL[kk * NC + c], omk, 1.f);  // bank c%32, conflict-free
            const float e   = exp2f(pre * -L2E_40);
            srun += e;
            trun = fmaf(e, pre, trun);
        };
        #pragma unroll
        for (int kq = 0; kq < 16; ++kq) {
            const float4 om4 = om4p[kq];          // broadcast, imm offset
            ACC(om4.x, 4 * kq + 0);
            ACC(om4.y, 4 * kq + 1);
            ACC(om4.z, 4 * kq + 2);
            ACC(om4.w, 4 * kq + 3);
        }
        const float inter = trun * __builtin_amdgcn_rcpf(srun);
        out[INTER_OFF + gpt * NC + c] = inter;

        // Union: softmax(pu*40)-weighted sum across the wave's 64 lanes
        const float pu = Uw[b * NC + c] * inter;
        float umax = pu;
        #pragma unroll
        for (int off = 32; off > 0; off >>= 1)
            umax = fmaxf(umax, __shfl_xor(umax, off, 64));
        const float e = exp2f((pu - umax) * L2E_40);
        float s1 = e, s2 = e * pu;
        #pragma unroll
        for (int off = 32; off > 0; off >>= 1) {
            s1 += __shfl_xor(s1, off, 64);
            s2 += __shfl_xor(s2, off, 64);
        }
        if (lane == 0) out[OCC_OFF + gpt] = s2 * __builtin_amdgcn_rcpf(s1);
    }
}

extern "C" void kernel_launch(void* const* d_in, const int* in_sizes, int n_in,
                              void* d_out, int out_size, void* d_ws, size_t ws_size,
                              hipStream_t stream) {
    const float* pts  = (const float*)d_in[0];
    const float* pp   = (const float*)d_in[1];
    const float* Wint = (const float*)d_in[2];
    const float* Uw   = (const float*)d_in[3];
    // d_in[4] = is_training (always 1 in this harness) -> training path hardcoded.
    float* out = (float*)d_out;
    (void)d_ws; (void)ws_size;   // workspace unused (curve table generated in LDS)

    const int grid = (NB * NM) / PPB;          // 1024 blocks x 512 threads
    extrude_net_fused<<<grid, 512, 0, stream>>>(pts, pp, Wint, Uw, out);
}